// Round 3
// baseline (313.542 us; speedup 1.0000x reference)
//
#include <hip/hip_runtime.h>

// Householder reflection: out[b,:] = z[b,:] - 2*v[b,:]*(v.z)/(v.v)
// B=8192 rows, L=4096 fp32. Baseline was latency/occupancy-bound
// (35% occ, 29% HBM): 32 KiB LDS staging capped residency at 4 blocks/CU.
// This version stages the row in REGISTERS across the reduction barrier
// (16 VGPRs), drops bulk LDS entirely (64 B reduction scratch only), uses
// one barrier, and streams the output with non-temporal stores so v/z can
// stay resident in the 256 MiB L3 across dispatches.
//
// NOTE: __builtin_nontemporal_store requires a NATIVE clang vector type —
// HIP's float4 (HIP_vector_type class) is rejected. Use ext_vector_type.

#define L_DIM 4096
#define BLOCK 512
#define VEC (L_DIM / 4)            // 1024 float4 per row
#define PER_THREAD (VEC / BLOCK)   // 2 float4 per thread per array
#define NWAVES (BLOCK / 64)        // 8 waves per block

typedef float f4 __attribute__((ext_vector_type(4)));

__global__ __launch_bounds__(BLOCK) void householder_kernel(
    const float* __restrict__ v,
    const float* __restrict__ z,
    float* __restrict__ out,
    int B)
{
    __shared__ float s_red[2][NWAVES];   // 64 B — only LDS in the kernel

    const int row = blockIdx.x;
    if (row >= B) return;
    const size_t base = (size_t)row * L_DIM;
    const f4* v4 = (const f4*)(v + base);
    const f4* z4 = (const f4*)(z + base);
    f4* o4 = (f4*)(out + base);

    // Pass 1: load row into registers (coalesced), partial dot products.
    f4 a[PER_THREAD], b[PER_THREAD];
    #pragma unroll
    for (int k = 0; k < PER_THREAD; ++k) {
        const int i = threadIdx.x + k * BLOCK;
        a[k] = v4[i];
        b[k] = z4[i];
    }

    float vz = 0.0f, vv = 0.0f;
    #pragma unroll
    for (int k = 0; k < PER_THREAD; ++k) {
        vz = fmaf(a[k].x, b[k].x, vz); vz = fmaf(a[k].y, b[k].y, vz);
        vz = fmaf(a[k].z, b[k].z, vz); vz = fmaf(a[k].w, b[k].w, vz);
        vv = fmaf(a[k].x, a[k].x, vv); vv = fmaf(a[k].y, a[k].y, vv);
        vv = fmaf(a[k].z, a[k].z, vv); vv = fmaf(a[k].w, a[k].w, vv);
    }

    // Wave (64-lane) shuffle reduction.
    #pragma unroll
    for (int off = 32; off > 0; off >>= 1) {
        vz += __shfl_down(vz, off, 64);
        vv += __shfl_down(vv, off, 64);
    }

    const int wave = threadIdx.x >> 6;
    if ((threadIdx.x & 63) == 0) {
        s_red[0][wave] = vz;
        s_red[1][wave] = vv;
    }
    __syncthreads();   // single barrier; a[]/b[] stay live in VGPRs

    // Every thread sums the 8 wave partials (broadcast LDS reads, no conflict).
    float tvz = 0.0f, tvv = 0.0f;
    #pragma unroll
    for (int w = 0; w < NWAVES; ++w) {
        tvz += s_red[0][w];
        tvv += s_red[1][w];
    }
    const float s = -2.0f * tvz / tvv;

    // Pass 2: out = z + s*v from registers; non-temporal store (output is
    // never re-read — don't let it evict v/z from L3).
    #pragma unroll
    for (int k = 0; k < PER_THREAD; ++k) {
        const int i = threadIdx.x + k * BLOCK;
        f4 r;
        r.x = fmaf(s, a[k].x, b[k].x);
        r.y = fmaf(s, a[k].y, b[k].y);
        r.z = fmaf(s, a[k].z, b[k].z);
        r.w = fmaf(s, a[k].w, b[k].w);
        __builtin_nontemporal_store(r, &o4[i]);
    }
}

extern "C" void kernel_launch(void* const* d_in, const int* in_sizes, int n_in,
                              void* d_out, int out_size, void* d_ws, size_t ws_size,
                              hipStream_t stream) {
    const float* v = (const float*)d_in[0];
    const float* z = (const float*)d_in[1];
    float* out = (float*)d_out;
    const int B = in_sizes[0] / L_DIM;   // 8192 rows
    householder_kernel<<<B, BLOCK, 0, stream>>>(v, z, out, B);
}

// Round 4
// 308.654 us; speedup vs baseline: 1.0158x; 1.0158x over previous
//
#include <hip/hip_runtime.h>

// Householder reflection: out[b,:] = z[b,:] - 2*v[b,:]*(v.z)/(v.v)
// B=8192 rows, L=4096 fp32.
// R0/R3 post-mortem: occupancy was NOT the bottleneck (16 vs 24 waves/CU,
// same ~2.2 TB/s). The limiter is memory-ISSUE duty cycle: each block bursts
// its loads, then spends ~2500 cycles in a lockstep serial phase (fma chain,
// 12 dependent shuffles, barrier, LDS round trip, stores) issuing nothing.
// ~3 independent blocks/CU * ~300 issue-cycles / ~2800-cycle lifetime ~= 32%
// duty == the measured 35% of achievable HBM BW.
// Fix: persistent grid-stride blocks, software-pipelined rows — issue row
// r+1's loads into a second register buffer BEFORE row r's reduce/barrier/
// store phase, so memory issue overlaps the serial phase continuously.
// s_red is parity-double-buffered so one barrier per row suffices.

#define L_DIM 4096
#define BLOCK 256
#define VEC (L_DIM / 4)            // 1024 float4 per row
#define PER_THREAD (VEC / BLOCK)   // 4 float4 per thread per array
#define NWAVES (BLOCK / 64)        // 4 waves per block

typedef float f4 __attribute__((ext_vector_type(4)));

__device__ __forceinline__ void load_row(
    const float* __restrict__ v, const float* __restrict__ z,
    size_t row, int tid,
    f4 (&A)[PER_THREAD], f4 (&Bv)[PER_THREAD])
{
    const f4* v4 = (const f4*)(v + row * L_DIM);
    const f4* z4 = (const f4*)(z + row * L_DIM);
    #pragma unroll
    for (int k = 0; k < PER_THREAD; ++k) {
        const int i = tid + k * BLOCK;   // coalesced
        A[k]  = v4[i];
        Bv[k] = z4[i];
    }
}

template <int PAR>
__device__ __forceinline__ void process_row(
    float* __restrict__ out, size_t row, int tid,
    const f4 (&A)[PER_THREAD], const f4 (&Bv)[PER_THREAD],
    float (&s_red)[2][2][NWAVES])
{
    float vz = 0.0f, vv = 0.0f;
    #pragma unroll
    for (int k = 0; k < PER_THREAD; ++k) {
        vz = fmaf(A[k].x, Bv[k].x, vz); vz = fmaf(A[k].y, Bv[k].y, vz);
        vz = fmaf(A[k].z, Bv[k].z, vz); vz = fmaf(A[k].w, Bv[k].w, vz);
        vv = fmaf(A[k].x, A[k].x, vv);  vv = fmaf(A[k].y, A[k].y, vv);
        vv = fmaf(A[k].z, A[k].z, vv);  vv = fmaf(A[k].w, A[k].w, vv);
    }

    // Wave (64-lane) shuffle reduction.
    #pragma unroll
    for (int off = 32; off > 0; off >>= 1) {
        vz += __shfl_down(vz, off, 64);
        vv += __shfl_down(vv, off, 64);
    }

    const int wave = tid >> 6;
    if ((tid & 63) == 0) {
        s_red[PAR][0][wave] = vz;
        s_red[PAR][1][wave] = vv;
    }
    __syncthreads();   // one barrier/row; parity buffer makes 2nd barrier unneeded

    float tvz = 0.0f, tvv = 0.0f;
    #pragma unroll
    for (int w = 0; w < NWAVES; ++w) {
        tvz += s_red[PAR][0][w];
        tvv += s_red[PAR][1][w];
    }
    const float s = -2.0f * tvz / tvv;

    f4* o4 = (f4*)(out + row * L_DIM);
    #pragma unroll
    for (int k = 0; k < PER_THREAD; ++k) {
        const int i = tid + k * BLOCK;
        f4 r;
        r.x = fmaf(s, A[k].x, Bv[k].x);
        r.y = fmaf(s, A[k].y, Bv[k].y);
        r.z = fmaf(s, A[k].z, Bv[k].z);
        r.w = fmaf(s, A[k].w, Bv[k].w);
        o4[i] = r;
    }
}

__global__ __launch_bounds__(BLOCK) void householder_kernel(
    const float* __restrict__ v,
    const float* __restrict__ z,
    float* __restrict__ out,
    int B)
{
    __shared__ float s_red[2][2][NWAVES];   // [parity][vz/vv][wave], 64 B

    const int tid = threadIdx.x;
    const int g = gridDim.x;
    int r = blockIdx.x;
    if (r >= B) return;

    // Two named register row-buffers (static indexing only — no runtime
    // buffer index, else they go to scratch).
    f4 a0[PER_THREAD], b0[PER_THREAD], a1[PER_THREAD], b1[PER_THREAD];
    load_row(v, z, (size_t)r, tid, a0, b0);

    for (;;) {
        const int r1 = r + g;
        if (r1 < B) load_row(v, z, (size_t)r1, tid, a1, b1);  // prefetch (uniform branch)
        process_row<0>(out, (size_t)r, tid, a0, b0, s_red);
        if (r1 >= B) return;

        const int r2 = r1 + g;
        if (r2 < B) load_row(v, z, (size_t)r2, tid, a0, b0);  // prefetch
        process_row<1>(out, (size_t)r1, tid, a1, b1, s_red);
        if (r2 >= B) return;
        r = r2;
    }
}

extern "C" void kernel_launch(void* const* d_in, const int* in_sizes, int n_in,
                              void* d_out, int out_size, void* d_ws, size_t ws_size,
                              hipStream_t stream) {
    const float* v = (const float*)d_in[0];
    const float* z = (const float*)d_in[1];
    float* out = (float*)d_out;
    const int B = in_sizes[0] / L_DIM;        // 8192 rows
    const int grid = (B < 2048) ? B : 2048;   // persistent-ish: ~4 rows/block
    householder_kernel<<<grid, BLOCK, 0, stream>>>(v, z, out, B);
}